// Round 1
// 74.998 us; speedup vs baseline: 1.0640x; 1.0640x over previous
//
#include <hip/hip_runtime.h>

// PixelVectorExtractor: one transformer encoder layer over per-pixel 7x7
// windows in a 30x30 canvas (S=900, D=11). Structure exploited:
//  - only 49/900 rows nonzero; 851 zero rows share ONE output vector.
//  - zero-score keys: +851 to softmax denom, nothing to numerator.
// v6 (this round): row = 16-lane group. 832 threads = 13 waves, 50 rows,
// 4 rows/wave. Phases 2-8 are wave-local: 10 __syncthreads -> 3; row
// reductions (softmax denom, LN1, LN2) via __shfl_xor in registers;
// x1/x1n/y/den never touch LDS. sW2/sH padded to 68 floats (11-way ->
// 2-way bank aliasing); within a wave only 16 consecutive rows are read
// at stride 48B -> <=2-way everywhere (free per m136). W1/Q rows hoisted
// to registers and reused across unrolled iterations.

#define D 11
#define ROWP 12      // padded row length (3 x float4), pad element = 0
#define NW 49
#define NR 50
#define NWP 52       // padded score-row length (13 x float4), pads = 0
#define FFD 64
#define W2P 68       // sW2 row pad: 68 dwords -> bank stride 4, 2-way max
#define HP  68       // sH row pad, same reason
#define CIN 10
#define SEQ 900
#define NB 256
#define TPB 832      // 13 waves; row r = tid>>4 (r<50), d = tid&15

__device__ __forceinline__ float dot12(const float4* a, const float4* b) {
    float4 s = make_float4(0.f, 0.f, 0.f, 0.f);
    #pragma unroll
    for (int i = 0; i < 3; ++i) {
        float4 x = a[i], y = b[i];
        s.x += x.x * y.x; s.y += x.y * y.y; s.z += x.z * y.z; s.w += x.w * y.w;
    }
    return s.x + s.y + s.z + s.w;
}

// Wave-local producer->consumer fence: lanes of one wave exchange through
// LDS. Wave is lockstep; we only need the DS ops drained and the compiler
// forbidden from reordering memory ops across the point.
__device__ __forceinline__ void wave_sync() {
    __builtin_amdgcn_wave_barrier();
    asm volatile("s_waitcnt lgkmcnt(0)" ::: "memory");
    __builtin_amdgcn_wave_barrier();
}

__global__ __launch_bounds__(TPB) void pve_kernel(
    const float* __restrict__ gx,     // [10,16,16]
    const float* __restrict__ gWqkv,  // [33,11]
    const float* __restrict__ gWo,    // [11,11]
    const float* __restrict__ gW1,    // [64,11]
    const float* __restrict__ gW2,    // [11,64]
    const float* __restrict__ gln1,   // [11]
    const float* __restrict__ gln2,   // [11]
    float* __restrict__ out)          // [256,10,900]
{
    __shared__ __align__(16) float sQ[33 * ROWP];    // Wqkv rows, padded
    __shared__ __align__(16) float sWo[D * ROWP];
    __shared__ __align__(16) float sW1[FFD * ROWP];
    __shared__ __align__(16) float sW2[D * W2P];     // rows padded to 68
    __shared__ __align__(16) float sSeq[NR][ROWP];
    __shared__ __align__(16) float sK[NW][ROWP];
    __shared__ __align__(16) float sVt[D][NWP];      // V transposed, [d][t]
    __shared__ __align__(16) float sQr[NR][ROWP];
    __shared__ __align__(16) float sE[NR][NWP];      // exp(scores), pads = 0
    __shared__ __align__(16) float sNum[NR][ROWP];
    __shared__ __align__(16) float sX1n[NR][ROWP];
    __shared__ __align__(16) float sH[NR][HP];       // first 64 cols used
    __shared__ __align__(16) float sR[NR][ROWP];

    const int tid = threadIdx.x;
    const int b = blockIdx.x;
    const int h = b >> 4;
    const int w = b & 15;

    const int r = tid >> 4;          // row, valid when < 50
    const int d = tid & 15;          // lane-in-row; real dims d < 11
    const bool rowv = (r < NR);
    const bool dv = (d < D);

    // ---- phase 0: stage weights (zero-padded rows) + seq + per-lane LN w ----
    for (int i = tid; i < 33 * ROWP; i += TPB) {
        const int rr = i / ROWP, cc = i - rr * ROWP;
        sQ[i] = (cc < D) ? gWqkv[rr * D + cc] : 0.f;
    }
    for (int i = tid; i < D * ROWP; i += TPB) {
        const int rr = i / ROWP, cc = i - rr * ROWP;
        sWo[i] = (cc < D) ? gWo[rr * D + cc] : 0.f;
    }
    for (int i = tid; i < FFD * ROWP; i += TPB) {
        const int rr = i / ROWP, cc = i - rr * ROWP;
        sW1[i] = (cc < D) ? gW1[rr * D + cc] : 0.f;
    }
    for (int i = tid; i < D * W2P; i += TPB) {
        const int rr = i / W2P, cc = i - rr * W2P;
        sW2[i] = (cc < FFD) ? gW2[rr * FFD + cc] : 0.f;
    }
    float lnw1 = 0.f, lnw2 = 0.f;
    if (dv) { lnw1 = gln1[d]; lnw2 = gln2[d]; }

    float xin = 0.f;                 // this lane's input element, kept in reg
    if (rowv) {
        if (dv) {
            if (r < NW) {
                const int i7 = r / 7, j7 = r - i7 * 7;
                const int y = h + i7, xx = w + j7;
                const bool inter = (y >= 3) && (y < 19) && (xx >= 3) && (xx < 19);
                const int base = inter ? ((y - 3) * 16 + (xx - 3)) : 0;
                if (d < CIN) xin = inter ? gx[d * 256 + base] : 0.0f;
                else         xin = inter ? 0.0f : 1.0f;     // mask channel
            }
            sSeq[r][d] = xin;
        } else if (d == D) {
            sSeq[r][D] = 0.f;        // row pad
        }
    }
    __syncthreads();                 // barrier 1: weights + seq staged

    // ---- phase 1: qkv projection; K,V are cross-wave -> block barrier ----
    if (rowv) {
        if (dv) {
            const float4* sv = (const float4*)&sSeq[r][0];
            const float aq = dot12(sv, (const float4*)&sQ[d * ROWP]);
            const float ak = dot12(sv, (const float4*)&sQ[(D + d) * ROWP]);
            const float av = dot12(sv, (const float4*)&sQ[(2 * D + d) * ROWP]);
            sQr[r][d] = aq;
            if (r < NW) { sK[r][d] = ak; sVt[d][r] = av; }
            else { sVt[d][NW] = 0.f; sVt[d][NW + 1] = 0.f; sVt[d][NW + 2] = 0.f; }
        } else if (d == D) {
            sQr[r][D] = 0.f;
            if (r < NW) sK[r][D] = 0.f;
        }
    }
    __syncthreads();                 // barrier 2: sK / sVt complete

    // ---- phase 2: scores + exp + denom, row-local (16 lanes x 4 tt) ----
    float den = 851.0f;
    if (rowv) {
        const float scale = 0.30151134457776363f;   // 1/sqrt(11)
        const float4* qv = (const float4*)&sQr[r][0];
        const float4 q0 = qv[0], q1 = qv[1], q2 = qv[2];  // hoisted Q row
        float psum = 0.f;
        #pragma unroll
        for (int it = 0; it < 4; ++it) {
            const int tt = d + (it << 4);
            if (tt < NWP) {
                float e = 0.f;
                if (tt < NW) {
                    const float4* kv = (const float4*)&sK[tt][0];
                    const float4 k0 = kv[0], k1 = kv[1], k2 = kv[2];
                    const float s =
                        q0.x*k0.x + q0.y*k0.y + q0.z*k0.z + q0.w*k0.w +
                        q1.x*k1.x + q1.y*k1.y + q1.z*k1.z + q1.w*k1.w +
                        q2.x*k2.x + q2.y*k2.y + q2.z*k2.z + q2.w*k2.w;
                    e = __expf(s * scale);
                }
                sE[r][tt] = e;       // pads (49..51) get exactly 0
                psum += e;
            }
        }
        psum += __shfl_xor(psum, 8, 16);
        psum += __shfl_xor(psum, 4, 16);
        psum += __shfl_xor(psum, 2, 16);
        psum += __shfl_xor(psum, 1, 16);
        den += psum;                 // every lane of the row has den in reg
    }
    wave_sync();

    // ---- phase 3: softmax numerator, row-local ----
    if (rowv) {
        if (dv) {
            const float4* ev = (const float4*)&sE[r][0];
            const float4* vv = (const float4*)&sVt[d][0];
            float4 an = make_float4(0.f, 0.f, 0.f, 0.f);
            #pragma unroll
            for (int i = 0; i < 13; ++i) {
                const float4 e = ev[i], v = vv[i];
                an.x += e.x * v.x; an.y += e.y * v.y;
                an.z += e.z * v.z; an.w += e.w * v.w;
            }
            sNum[r][d] = an.x + an.y + an.z + an.w;
        } else if (d == D) {
            sNum[r][D] = 0.f;
        }
    }
    wave_sync();

    // ---- phase 4+5: out-proj + residual + LN1, all in registers ----
    float x1 = 0.f;
    if (rowv && dv) {
        const float acc = dot12((const float4*)&sNum[r][0],
                                (const float4*)&sWo[d * ROWP]);
        x1 = xin + acc / den;
    }
    {   // LN1 stats over the 16-lane row group (d>=11 contribute 0)
        float s1 = x1, s2 = x1 * x1;
        s1 += __shfl_xor(s1, 8, 16); s2 += __shfl_xor(s2, 8, 16);
        s1 += __shfl_xor(s1, 4, 16); s2 += __shfl_xor(s2, 4, 16);
        s1 += __shfl_xor(s1, 2, 16); s2 += __shfl_xor(s2, 2, 16);
        s1 += __shfl_xor(s1, 1, 16); s2 += __shfl_xor(s2, 1, 16);
        const float m   = s1 * (1.0f / 11.0f);
        const float var = s2 * (1.0f / 11.0f) - m * m;
        x1 = (x1 - m) * rsqrtf(var + 1e-5f) * lnw1;    // now x1 == x1n
    }
    if (rowv) {
        if (dv) sX1n[r][d] = x1;
        else if (d == D) sX1n[r][D] = 0.f;
    }
    wave_sync();

    // ---- phase 6: FF hidden, row-local (16 lanes x 4 ff) ----
    if (rowv) {
        const float4* xv = (const float4*)&sX1n[r][0];
        const float4 xa = xv[0], xb = xv[1], xc = xv[2]; // hoisted x1n row
        #pragma unroll
        for (int it = 0; it < 4; ++it) {
            const int ff = d + (it << 4);
            const float4* wv = (const float4*)&sW1[ff * ROWP];
            const float4 w0 = wv[0], w1 = wv[1], w2 = wv[2];
            const float acc =
                xa.x*w0.x + xa.y*w0.y + xa.z*w0.z + xa.w*w0.w +
                xb.x*w1.x + xb.y*w1.y + xb.z*w1.z + xb.w*w1.w +
                xc.x*w2.x + xc.y*w2.y + xc.z*w2.z + xc.w*w2.w;
            sH[r][ff] = fmaxf(acc, 0.0f);
        }
    }
    wave_sync();

    // ---- phase 7+8: FF out + residual + LN2, in registers ----
    float yv = 0.f;
    if (rowv && dv) {
        const float4* hv = (const float4*)&sH[r][0];
        const float4* wv = (const float4*)&sW2[d * W2P];
        float4 a4 = make_float4(0.f, 0.f, 0.f, 0.f);
        #pragma unroll
        for (int i = 0; i < 16; ++i) {
            const float4 hh = hv[i], ww = wv[i];
            a4.x += hh.x * ww.x; a4.y += hh.y * ww.y;
            a4.z += hh.z * ww.z; a4.w += hh.w * ww.w;
        }
        yv = x1 + a4.x + a4.y + a4.z + a4.w;
    }
    {   // LN2 stats
        float s1 = yv, s2 = yv * yv;
        s1 += __shfl_xor(s1, 8, 16); s2 += __shfl_xor(s2, 8, 16);
        s1 += __shfl_xor(s1, 4, 16); s2 += __shfl_xor(s2, 4, 16);
        s1 += __shfl_xor(s1, 2, 16); s2 += __shfl_xor(s2, 2, 16);
        s1 += __shfl_xor(s1, 1, 16); s2 += __shfl_xor(s2, 1, 16);
        const float m   = s1 * (1.0f / 11.0f);
        const float var = s2 * (1.0f / 11.0f) - m * m;
        if (rowv && dv) sR[r][d] = (yv - m) * rsqrtf(var + 1e-5f) * lnw2;
    }
    __syncthreads();                 // barrier 3: sR complete for epilogue

    // ---- phase 9: epilogue, out[b,c,s] as float4 (2250 per block) ----
    float4* ob4 = (float4*)(out + b * (CIN * SEQ));
    #pragma unroll
    for (int k = 0; k < 3; ++k) {
        const int qi = tid + k * TPB;
        if (qi < 2250) {
            const int c  = qi / 225;             // 225 float4 per channel
            const int s0 = (qi - c * 225) * 4;
            float4 v4;
            float* pv = (float*)&v4;
            #pragma unroll
            for (int u = 0; u < 4; ++u) {
                const int s = s0 + u;
                const int i = s / 30;
                const int j = s - i * 30;
                pv[u] = (i < 7 && j < 7) ? sR[i * 7 + j][c] : sR[NW][c];
            }
            ob4[qi] = v4;
        }
    }
}

extern "C" void kernel_launch(void* const* d_in, const int* in_sizes, int n_in,
                              void* d_out, int out_size, void* d_ws, size_t ws_size,
                              hipStream_t stream) {
    (void)in_sizes; (void)n_in; (void)out_size; (void)d_ws; (void)ws_size;
    const float* x    = (const float*)d_in[0];
    const float* Wqkv = (const float*)d_in[1];
    const float* Wo   = (const float*)d_in[2];
    const float* W1   = (const float*)d_in[3];
    const float* W2   = (const float*)d_in[4];
    const float* ln1  = (const float*)d_in[5];
    const float* ln2  = (const float*)d_in[6];
    pve_kernel<<<NB, TPB, 0, stream>>>(x, Wqkv, Wo, W1, W2, ln1, ln2,
                                       (float*)d_out);
}